// Round 13
// baseline (52.003 us; speedup 1.0000x reference)
//
#include <hip/hip_runtime.h>

#define H 128
#define NPOS 10
#define ROWSB 64
#define BLOCK 512

using bf16x8 = __attribute__((ext_vector_type(8))) short;
using f32x4  = __attribute__((ext_vector_type(4))) float;

__device__ __forceinline__ unsigned short f2bf(float f) {
  unsigned u = __float_as_uint(f);
  u += 0x7FFFu + ((u >> 16) & 1u);   // round-to-nearest-even
  return (unsigned short)(u >> 16);
}
__device__ __forceinline__ float sigm(float x) {
  return __builtin_amdgcn_rcpf(1.0f + __builtin_amdgcn_exp2f(-1.44269504f * x));
}
__device__ __forceinline__ float tanh_f(float x) {
  return 2.0f * __builtin_amdgcn_rcpf(1.0f + __builtin_amdgcn_exp2f(-2.88539008f * x)) - 1.0f;
}

// K1: weights prep (k-major fragment layout) + per-block pos histogram.
// wt elem offset = (((p*4+kk)*4 + lhi)*512 + j)*8 + e  where k = kk*32+lhi*8+e,
// j<128 -> u-gate col j (W_f);  j>=128 -> iou row j-128 (W_iou).
__global__ void prep_wt(const float* __restrict__ Wf, const float* __restrict__ Wiou,
                        unsigned short* __restrict__ wt,
                        const int* __restrict__ posp, int* __restrict__ hist2,
                        int N, int nhb) {
  int b = blockIdx.x, t = threadIdx.x;
  if (b < NPOS * 16) {
    __shared__ float tile[32][33];
    int p = b >> 4, jt = (b >> 2) & 3, kt = b & 3;
    int tx = t & 31, ty = t >> 5;            // 32 x 8
    #pragma unroll
    for (int it = 0; it < 4; ++it) {
      int krow = kt * 32 + ty + it * 8;
      int j = jt * 32 + tx;
      tile[ty + it * 8][tx] = Wf[(size_t)(p * H + krow) * H + j];
    }
    __syncthreads();
    #pragma unroll
    for (int it = 0; it < 4; ++it) {
      int j2 = jt * 32 + ty + it * 8;        // u-gate col
      size_t dst = (((size_t)(p * 4 + kt) * 4 + (tx >> 3)) * 512 + j2) * 8 + (tx & 7);
      wt[dst] = f2bf(tile[tx][ty + it * 8]);
    }
  } else if (b < NPOS * 16 + (NPOS * 384 * H) / 256) {
    int id = (b - NPOS * 16) * 256 + t;      // < 10*384*128
    int p = id / 49152;
    int r = id - p * 49152;                  // (j-128)*128 + k
    int j = 128 + (r >> 7);
    int k = r & 127;
    float v = Wiou[(size_t)(r >> 7) * (NPOS * H) + p * H + k];
    size_t dst = (((size_t)(p * 4 + (k >> 5)) * 4 + ((k >> 3) & 3)) * 512 + j) * 8 + (k & 7);
    wt[dst] = f2bf(v);
  } else {
    int hb = b - (NPOS * 16 + (NPOS * 384 * H) / 256);
    __shared__ int c[NPOS];
    if (t < NPOS) c[t] = 0;
    __syncthreads();
    int i = hb * 256 + t;
    if (i < N) atomicAdd(&c[posp[i]], 1);    // LDS atomic only
    __syncthreads();
    if (t < NPOS) hist2[hb * 16 + t] = c[t];
  }
}

// K2: wave-parallel scans (10 waves, wave w owns pos w).
__global__ void scan_build(const int* __restrict__ hist2, int nhb,
                           int* __restrict__ off2,
                           int* __restrict__ blkpos, int* __restrict__ blkgs,
                           int* __restrict__ blkcnt, int maxb) {
  __shared__ int tot[NPOS], base[NPOS + 1], bb[NPOS + 1];
  int t = threadIdx.x;
  int w = t >> 6, l = t & 63;
  if (w < NPOS) {
    int b0 = 2 * l, b1 = 2 * l + 1;
    int a  = (b0 < nhb) ? hist2[b0 * 16 + w] : 0;
    int bv = (b1 < nhb) ? hist2[b1 * 16 + w] : 0;
    int s = a + bv, sc = s;
    #pragma unroll
    for (int off = 1; off < 64; off <<= 1) {
      int u = __shfl_up(sc, off);
      if (l >= off) sc += u;
    }
    int excl = sc - s;
    if (b0 < nhb) off2[b0 * 16 + w] = excl;
    if (b1 < nhb) off2[b1 * 16 + w] = excl + a;
    if (l == 63) tot[w] = sc;
  }
  __syncthreads();
  if (t == 0) {
    int run = 0, rb = 0;
    for (int p = 0; p < NPOS; ++p) {
      base[p] = run; bb[p] = rb;
      run += tot[p];
      rb += (tot[p] + ROWSB - 1) / ROWSB;
    }
    base[NPOS] = run; bb[NPOS] = rb;
  }
  __syncthreads();
  for (int i = t; i < nhb * NPOS; i += 640) {
    int b = i / NPOS, p = i - b * NPOS;
    off2[b * 16 + p] += base[p];
  }
  int nb = bb[NPOS];
  for (int b = t; b < maxb; b += 640) {
    if (b < nb) {
      int p = 0;
      while (bb[p + 1] <= b) ++p;
      int s = (b - bb[p]) * ROWSB;
      blkpos[b] = p;
      blkgs[b] = base[p] + s;
      blkcnt[b] = min(ROWSB, tot[p] - s);
    } else {
      blkpos[b] = -1;
    }
  }
}

// K3: scatter (LDS atomics + precomputed per-(block,pos) bases).
// order entry packs: g | mask<<16 | (depth==1)<<17 | (depth==2)<<18
__global__ void scatter_idx(const int* __restrict__ posp, const int* __restrict__ depthp,
                            const int* __restrict__ maskp, const int* __restrict__ off2,
                            unsigned* __restrict__ order, int N) {
  __shared__ int c[NPOS], basearr[NPOS];
  int hb = blockIdx.x, t = threadIdx.x;
  if (t < NPOS) { c[t] = 0; basearr[t] = off2[hb * 16 + t]; }
  __syncthreads();
  int i = hb * 256 + t;
  int p = -1, r = 0;
  unsigned e = 0;
  if (i < N) {
    p = posp[i];
    r = atomicAdd(&c[p], 1);                 // LDS atomic only
    int d = depthp[i];
    int mk = maskp[i];
    e = (unsigned)i | ((unsigned)mk << 16) |
        ((unsigned)(d == 1) << 17) | ((unsigned)(d == 2) << 18);
  }
  __syncthreads();
  if (p >= 0) order[basearr[p] + r] = e;
}

// K4: 64-row blocks, kk-outer, B-slab in LDS, T14 async staging, raw barriers
// (no vmcnt drains), epilogue gathers issued under last MFMA round.
__global__ __launch_bounds__(BLOCK, 3) void tree_lstm_main(
    const float* __restrict__ child_h, const float* __restrict__ child_c,
    const float* __restrict__ e1, const float* __restrict__ e2,
    const float* __restrict__ h_prev,
    const float* __restrict__ b_f, const float* __restrict__ b_iou,
    const unsigned short* __restrict__ wt,
    const unsigned* __restrict__ order, const int* __restrict__ blkpos,
    const int* __restrict__ blkgs, const int* __restrict__ blkcnt,
    float* __restrict__ out, int N) {

  const int b = blockIdx.x;
  const int p = blkpos[b];
  if (p < 0) return;
  const int gs = blkgs[b], cnth = blkcnt[b];

  __shared__ unsigned short hs[ROWSB * H];   // 16 KB, XOR-swizzled bf16 h_cat
  __shared__ unsigned short Bs[4 * 512 * 8]; // 32 KB, one kk-slab of B panel
  __shared__ unsigned rowg[ROWSB];

  const int t = threadIdx.x;
  const int wv = t >> 6, l = t & 63;
  const int l15 = l & 15, lhi = l >> 4;
  const int colr = wv * 16 + l15;            // wave's output column 0..127

  if (t < ROWSB) rowg[t] = (t < cnth) ? order[gs + t] : 0xFFFFFFFFu;
  asm volatile("s_waitcnt lgkmcnt(0)");
  __builtin_amdgcn_sched_barrier(0);
  __builtin_amdgcn_s_barrier();              // rowg visible (no vm drain)

  // ---- stage A: 64 rows x 128 bf16 ----
  #pragma unroll
  for (int i = 0; i < 2; ++i) {
    int id = i * BLOCK + t;
    int row = id >> 4, c8 = id & 15;
    unsigned e = rowg[row];
    float4 a0 = {0.f, 0.f, 0.f, 0.f}, a1 = {0.f, 0.f, 0.f, 0.f};
    if ((int)e >= 0) {
      int g = e & 0xFFFF;
      const float4* ph = (const float4*)(child_h + (size_t)g * H + c8 * 8);
      a0 = ph[0]; a1 = ph[1];
      if (e & (3u << 17)) {
        const float* ep = (e & (1u << 17)) ? e1 : e2;
        const float4* pe = (const float4*)(ep + (size_t)g * H + c8 * 8);
        float4 b0 = pe[0], b1 = pe[1];
        a0.x += b0.x; a0.y += b0.y; a0.z += b0.z; a0.w += b0.w;
        a1.x += b1.x; a1.y += b1.y; a1.z += b1.z; a1.w += b1.w;
      }
    }
    bf16x8 v;
    v[0] = (short)f2bf(a0.x); v[1] = (short)f2bf(a0.y);
    v[2] = (short)f2bf(a0.z); v[3] = (short)f2bf(a0.w);
    v[4] = (short)f2bf(a1.x); v[5] = (short)f2bf(a1.y);
    v[6] = (short)f2bf(a1.z); v[7] = (short)f2bf(a1.w);
    int wb = (row * 256 + c8 * 16) ^ ((row & 7) << 4);
    *(bf16x8*)((char*)hs + wb) = v;
  }

  // ---- stage Bs slab kk=0 (loads -> ds_write; own deps auto-waited) ----
  const unsigned short* wtp = wt + (size_t)p * 65536;
  {
    bf16x8 breg[4];
    #pragma unroll
    for (int i = 0; i < 4; ++i)
      breg[i] = *(const bf16x8*)(wtp + (i * BLOCK + t) * 8);
    #pragma unroll
    for (int i = 0; i < 4; ++i)
      *(bf16x8*)(Bs + (i * BLOCK + t) * 8) = breg[i];
  }
  asm volatile("s_waitcnt lgkmcnt(0)");
  __builtin_amdgcn_sched_barrier(0);
  __builtin_amdgcn_s_barrier();              // hs + Bs0 visible

  f32x4 acc[4][4] = {};
  unsigned gg[4][4]; float cc[4][4], hpv[4][4];

  #pragma unroll
  for (int kk = 0; kk < 4; ++kk) {
    bf16x8 nreg[4];
    if (kk < 3) {
      // T14: issue next slab's global loads BEFORE this kk's compute
      #pragma unroll
      for (int i = 0; i < 4; ++i)
        nreg[i] = *(const bf16x8*)(wtp + (kk + 1) * 16384 + (i * BLOCK + t) * 8);
    } else {
      // issue epilogue gathers; they land under this kk's MFMAs
      #pragma unroll
      for (int c = 0; c < 4; ++c)
        #pragma unroll
        for (int q = 0; q < 4; ++q) {
          int rr = c * 16 + lhi * 4 + q;
          unsigned e = (rr < cnth) ? rowg[rr] : 0xFFFFFFFFu;
          gg[c][q] = e;
          if ((int)e >= 0) {
            size_t gi = (size_t)(e & 0xFFFF) * H + colr;
            cc[c][q] = child_c[gi];
            hpv[c][q] = h_prev[gi];
          } else { cc[c][q] = 0.f; hpv[c][q] = 0.f; }
        }
    }

    bf16x8 bfr[4];
    #pragma unroll
    for (int g4 = 0; g4 < 4; ++g4)
      bfr[g4] = *(const bf16x8*)(Bs + ((lhi * 512) + (g4 * 128 + colr)) * 8);

    #pragma unroll
    for (int c = 0; c < 4; ++c) {
      const int arow = c * 16 + l15;
      int rb = (arow * 256 + kk * 64 + lhi * 16) ^ ((arow & 7) << 4);
      bf16x8 afr = *(const bf16x8*)((const char*)hs + rb);
      #pragma unroll
      for (int g4 = 0; g4 < 4; ++g4)
        acc[c][g4] = __builtin_amdgcn_mfma_f32_16x16x32_bf16(afr, bfr[g4], acc[c][g4], 0, 0, 0);
    }

    if (kk < 3) {
      asm volatile("s_waitcnt lgkmcnt(0)");  // this wave's Bs/hs reads retired
      __builtin_amdgcn_sched_barrier(0);
      __builtin_amdgcn_s_barrier();          // all waves done reading Bs
      #pragma unroll
      for (int i = 0; i < 4; ++i)
        *(bf16x8*)(Bs + (i * BLOCK + t) * 8) = nreg[i];  // waits own vmcnt only
      asm volatile("s_waitcnt lgkmcnt(0)");
      __builtin_amdgcn_sched_barrier(0);
      __builtin_amdgcn_s_barrier();          // new slab visible
    }
  }

  // ---- epilogue: D row = (l>>4)*4 + q, col = l&15 ----
  const size_t NH = (size_t)N * H;
  const float bfv = b_f[p * H + colr];
  const float b_i = b_iou[colr], b_o = b_iou[H + colr], b_g = b_iou[2 * H + colr];

  #pragma unroll
  for (int c = 0; c < 4; ++c)
    #pragma unroll
    for (int q = 0; q < 4; ++q) {
      if ((int)gg[c][q] >= 0) {
        size_t gi = (size_t)(gg[c][q] & 0xFFFF) * H + colr;
        float u  = acc[c][0][q] + bfv;
        float iv = acc[c][1][q] + b_i;
        float ov = acc[c][2][q] + b_o;
        float gv = acc[c][3][q] + b_g;
        float f = sigm(u);
        float credv = f * cc[c][q];
        float cnew = sigm(iv) * tanh_f(gv) + credv;
        float hnew = sigm(ov) * tanh_f(cnew);
        float m = (float)((gg[c][q] >> 16) & 1u);
        float hv = hpv[c][q] * m + (1.0f - m) * hnew;
        float cv = credv * m + (1.0f - m) * cnew;
        out[gi] = hv;
        out[NH + gi] = cv;
      }
    }
}

extern "C" void kernel_launch(void* const* d_in, const int* in_sizes, int n_in,
                              void* d_out, int out_size, void* d_ws, size_t ws_size,
                              hipStream_t stream) {
  const float* child_h = (const float*)d_in[0];
  const float* child_c = (const float*)d_in[1];
  const float* e1      = (const float*)d_in[2];
  const float* e2      = (const float*)d_in[3];
  const float* h_prev  = (const float*)d_in[4];
  const int*   posp    = (const int*)d_in[5];
  const int*   depthp  = (const int*)d_in[6];
  const int*   maskp   = (const int*)d_in[7];
  const float* W_f     = (const float*)d_in[8];
  const float* b_f     = (const float*)d_in[9];
  const float* W_iou   = (const float*)d_in[10];
  const float* b_iou   = (const float*)d_in[11];
  float* out = (float*)d_out;
  int N = in_sizes[0] / H;
  int nhb = (N + 255) / 256;
  int maxb = NPOS + N / ROWSB;

  // ws layout
  unsigned short* wt = (unsigned short*)d_ws;          // 655360 * 2B
  int* hist2  = (int*)((char*)d_ws + (size_t)NPOS * 512 * H * 2);
  int* off2   = hist2 + nhb * 16;
  int* blkpos = off2 + nhb * 16;
  int* blkgs  = blkpos + maxb;
  int* blkcnt = blkgs + maxb;
  unsigned* order = (unsigned*)(blkcnt + maxb);

  int prep_blocks = NPOS * 16 + (NPOS * 384 * H) / 256 + nhb;
  hipLaunchKernelGGL(prep_wt, dim3(prep_blocks), dim3(256), 0, stream,
                     W_f, W_iou, wt, posp, hist2, N, nhb);
  hipLaunchKernelGGL(scan_build, dim3(1), dim3(640), 0, stream,
                     hist2, nhb, off2, blkpos, blkgs, blkcnt, maxb);
  hipLaunchKernelGGL(scatter_idx, dim3(nhb), dim3(256), 0, stream,
                     posp, depthp, maskp, off2, order, N);
  hipLaunchKernelGGL(tree_lstm_main, dim3(maxb), dim3(BLOCK), 0, stream,
                     child_h, child_c, e1, e2, h_prev,
                     b_f, b_iou, wt, order, blkpos, blkgs, blkcnt, out, N);
}

// Round 14
// 44.894 us; speedup vs baseline: 1.1583x; 1.1583x over previous
//
#include <hip/hip_runtime.h>

#define H 128
#define NPOS 10
#define ROWSB 32
#define BLOCK 512

using bf16x8 = __attribute__((ext_vector_type(8))) short;
using f32x4  = __attribute__((ext_vector_type(4))) float;

__device__ __forceinline__ unsigned short f2bf(float f) {
  unsigned u = __float_as_uint(f);
  u += 0x7FFFu + ((u >> 16) & 1u);   // round-to-nearest-even
  return (unsigned short)(u >> 16);
}
__device__ __forceinline__ float bf2f(unsigned short s) {
  return __uint_as_float(((unsigned)s) << 16);
}
__device__ __forceinline__ float sigm(float x) {
  return __builtin_amdgcn_rcpf(1.0f + __builtin_amdgcn_exp2f(-1.44269504f * x));
}
__device__ __forceinline__ float tanh_f(float x) {
  return 2.0f * __builtin_amdgcn_rcpf(1.0f + __builtin_amdgcn_exp2f(-2.88539008f * x)) - 1.0f;
}

// K1: weights prep (k-major fragment layout) + per-block pos histogram.
// wt elem offset = (((p*4+kk)*4 + lhi)*512 + j)*8 + e  where k = kk*32+lhi*8+e,
// j<128 -> u-gate col j (W_f);  j>=128 -> iou row j-128 (W_iou).
__global__ void prep_wt(const float* __restrict__ Wf, const float* __restrict__ Wiou,
                        unsigned short* __restrict__ wt,
                        const int* __restrict__ posp, int* __restrict__ hist2,
                        int N, int nhb) {
  int b = blockIdx.x, t = threadIdx.x;
  if (b < NPOS * 16) {
    __shared__ float tile[32][33];
    int p = b >> 4, jt = (b >> 2) & 3, kt = b & 3;
    int tx = t & 31, ty = t >> 5;            // 32 x 8
    #pragma unroll
    for (int it = 0; it < 4; ++it) {
      int krow = kt * 32 + ty + it * 8;
      int j = jt * 32 + tx;
      tile[ty + it * 8][tx] = Wf[(size_t)(p * H + krow) * H + j];
    }
    __syncthreads();
    #pragma unroll
    for (int it = 0; it < 4; ++it) {
      int j2 = jt * 32 + ty + it * 8;        // u-gate col
      size_t dst = (((size_t)(p * 4 + kt) * 4 + (tx >> 3)) * 512 + j2) * 8 + (tx & 7);
      wt[dst] = f2bf(tile[tx][ty + it * 8]);
    }
  } else if (b < NPOS * 16 + (NPOS * 384 * H) / 256) {
    int id = (b - NPOS * 16) * 256 + t;      // < 10*384*128
    int p = id / 49152;
    int r = id - p * 49152;                  // (j-128)*128 + k
    int j = 128 + (r >> 7);
    int k = r & 127;
    float v = Wiou[(size_t)(r >> 7) * (NPOS * H) + p * H + k];
    size_t dst = (((size_t)(p * 4 + (k >> 5)) * 4 + ((k >> 3) & 3)) * 512 + j) * 8 + (k & 7);
    wt[dst] = f2bf(v);
  } else {
    int hb = b - (NPOS * 16 + (NPOS * 384 * H) / 256);
    __shared__ int c[NPOS];
    if (t < NPOS) c[t] = 0;
    __syncthreads();
    int i = hb * 256 + t;
    if (i < N) atomicAdd(&c[posp[i]], 1);    // LDS atomic only
    __syncthreads();
    if (t < NPOS) hist2[hb * 16 + t] = c[t];
  }
}

// K2: wave-parallel scans (10 waves, wave w owns pos w).
__global__ void scan_build(const int* __restrict__ hist2, int nhb,
                           int* __restrict__ off2,
                           int* __restrict__ blkpos, int* __restrict__ blkgs,
                           int* __restrict__ blkcnt, int maxb) {
  __shared__ int tot[NPOS], base[NPOS + 1], bb[NPOS + 1];
  int t = threadIdx.x;
  int w = t >> 6, l = t & 63;
  if (w < NPOS) {
    int b0 = 2 * l, b1 = 2 * l + 1;
    int a  = (b0 < nhb) ? hist2[b0 * 16 + w] : 0;
    int bv = (b1 < nhb) ? hist2[b1 * 16 + w] : 0;
    int s = a + bv, sc = s;
    #pragma unroll
    for (int off = 1; off < 64; off <<= 1) {
      int u = __shfl_up(sc, off);
      if (l >= off) sc += u;
    }
    int excl = sc - s;
    if (b0 < nhb) off2[b0 * 16 + w] = excl;
    if (b1 < nhb) off2[b1 * 16 + w] = excl + a;
    if (l == 63) tot[w] = sc;
  }
  __syncthreads();
  if (t == 0) {
    int run = 0, rb = 0;
    for (int p = 0; p < NPOS; ++p) {
      base[p] = run; bb[p] = rb;
      run += tot[p];
      rb += (tot[p] + ROWSB - 1) / ROWSB;
    }
    base[NPOS] = run; bb[NPOS] = rb;
  }
  __syncthreads();
  for (int i = t; i < nhb * NPOS; i += 640) {
    int b = i / NPOS, p = i - b * NPOS;
    off2[b * 16 + p] += base[p];
  }
  int nb = bb[NPOS];
  for (int b = t; b < maxb; b += 640) {
    if (b < nb) {
      int p = 0;
      while (bb[p + 1] <= b) ++p;
      int s = (b - bb[p]) * ROWSB;
      blkpos[b] = p;
      blkgs[b] = base[p] + s;
      blkcnt[b] = min(ROWSB, tot[p] - s);
    } else {
      blkpos[b] = -1;
    }
  }
}

// K3: scatter (LDS atomics + precomputed per-(block,pos) bases).
// order entry packs: g | mask<<16 | (depth==1)<<17 | (depth==2)<<18
__global__ void scatter_idx(const int* __restrict__ posp, const int* __restrict__ depthp,
                            const int* __restrict__ maskp, const int* __restrict__ off2,
                            unsigned* __restrict__ order, int N) {
  __shared__ int c[NPOS], basearr[NPOS];
  int hb = blockIdx.x, t = threadIdx.x;
  if (t < NPOS) { c[t] = 0; basearr[t] = off2[hb * 16 + t]; }
  __syncthreads();
  int i = hb * 256 + t;
  int p = -1, r = 0;
  unsigned e = 0;
  if (i < N) {
    p = posp[i];
    r = atomicAdd(&c[p], 1);                 // LDS atomic only
    int d = depthp[i];
    int mk = maskp[i];
    e = (unsigned)i | ((unsigned)mk << 16) |
        ((unsigned)(d == 1) << 17) | ((unsigned)(d == 2) << 18);
  }
  __syncthreads();
  if (p >= 0) order[basearr[p] + r] = e;
}

// K4: main (R12 structure) + LDS gate transpose -> row-per-wave streaming
// epilogue: all scattered HBM traffic widened from 64B to 512B segments.
__global__ __launch_bounds__(BLOCK, 3) void tree_lstm_main(
    const float* __restrict__ child_h, const float* __restrict__ child_c,
    const float* __restrict__ e1, const float* __restrict__ e2,
    const float* __restrict__ h_prev,
    const float* __restrict__ b_f, const float* __restrict__ b_iou,
    const unsigned short* __restrict__ wt,
    const unsigned* __restrict__ order, const int* __restrict__ blkpos,
    const int* __restrict__ blkgs, const int* __restrict__ blkcnt,
    float* __restrict__ out, int N) {

  const int b = blockIdx.x;
  const int p = blkpos[b];
  if (p < 0) return;
  const int gs = blkgs[b], cnth = blkcnt[b];

  __shared__ unsigned short hs[ROWSB * H];   // 8 KB, XOR-swizzled bf16 h_cat
  __shared__ unsigned short Bs[4 * 512 * 8]; // 32 KB: B slab; then gate-transpose
  __shared__ unsigned rowg[ROWSB];

  const int t = threadIdx.x;
  const int wv = t >> 6, l = t & 63;
  const int l15 = l & 15, lhi = l >> 4;
  const int colr = wv * 16 + l15;            // wave's output column 0..127

  if (t < ROWSB) rowg[t] = (t < cnth) ? order[gs + t] : 0xFFFFFFFFu;
  __syncthreads();

  // ---- stage A: 32 rows x 128 bf16 (512B contiguous per row) ----
  {
    int row = t >> 4, c8 = t & 15;
    unsigned e = rowg[row];
    float4 a0 = {0.f, 0.f, 0.f, 0.f}, a1 = {0.f, 0.f, 0.f, 0.f};
    if ((int)e >= 0) {
      int g = e & 0xFFFF;
      const float4* ph = (const float4*)(child_h + (size_t)g * H + c8 * 8);
      a0 = ph[0]; a1 = ph[1];
      if (e & (3u << 17)) {
        const float* ep = (e & (1u << 17)) ? e1 : e2;
        const float4* pe = (const float4*)(ep + (size_t)g * H + c8 * 8);
        float4 b0 = pe[0], b1 = pe[1];
        a0.x += b0.x; a0.y += b0.y; a0.z += b0.z; a0.w += b0.w;
        a1.x += b1.x; a1.y += b1.y; a1.z += b1.z; a1.w += b1.w;
      }
    }
    bf16x8 v;
    v[0] = (short)f2bf(a0.x); v[1] = (short)f2bf(a0.y);
    v[2] = (short)f2bf(a0.z); v[3] = (short)f2bf(a0.w);
    v[4] = (short)f2bf(a1.x); v[5] = (short)f2bf(a1.y);
    v[6] = (short)f2bf(a1.z); v[7] = (short)f2bf(a1.w);
    int wb = (row * 256 + c8 * 16) ^ ((row & 7) << 4);
    *(bf16x8*)((char*)hs + wb) = v;
  }
  __syncthreads();

  f32x4 acc[2][4] = {};
  const unsigned short* wtp = wt + (size_t)p * 65536;

  #pragma unroll
  for (int kk = 0; kk < 4; ++kk) {
    if (kk) __syncthreads();
    #pragma unroll
    for (int i = 0; i < 4; ++i) {
      int eo = (i * BLOCK + t) * 8;
      *(bf16x8*)(Bs + eo) = *(const bf16x8*)(wtp + kk * 16384 + eo);
    }
    __syncthreads();

    bf16x8 bfr[4];
    #pragma unroll
    for (int g4 = 0; g4 < 4; ++g4)
      bfr[g4] = *(const bf16x8*)(Bs + ((lhi * 512) + (g4 * 128 + colr)) * 8);

    #pragma unroll
    for (int c = 0; c < 2; ++c) {
      const int arow = c * 16 + l15;
      int rb = (arow * 256 + kk * 64 + lhi * 16) ^ ((arow & 7) << 4);
      bf16x8 afr = *(const bf16x8*)((const char*)hs + rb);
      #pragma unroll
      for (int g4 = 0; g4 < 4; ++g4)
        acc[c][g4] = __builtin_amdgcn_mfma_f32_16x16x32_bf16(afr, bfr[g4], acc[c][g4], 0, 0, 0);
    }
  }
  __syncthreads();                            // Bs reads done; safe to overwrite

  // ---- gate transpose into Bs (bias applied; bf16 validated in R11) ----
  {
    const float bfv = b_f[p * H + colr];
    const float b_i = b_iou[colr], b_o = b_iou[H + colr], b_g = b_iou[2 * H + colr];
    #pragma unroll
    for (int c = 0; c < 2; ++c)
      #pragma unroll
      for (int q = 0; q < 4; ++q) {
        int r = c * 16 + lhi * 4 + q;
        Bs[((r * 4 + 0) << 7) + colr] = f2bf(acc[c][0][q] + bfv);
        Bs[((r * 4 + 1) << 7) + colr] = f2bf(acc[c][1][q] + b_i);
        Bs[((r * 4 + 2) << 7) + colr] = f2bf(acc[c][2][q] + b_o);
        Bs[((r * 4 + 3) << 7) + colr] = f2bf(acc[c][3][q] + b_g);
      }
  }
  __syncthreads();

  // ---- row-per-wave epilogue: 512B-contiguous gathers and stores ----
  const size_t NH = (size_t)N * H;
  const int c2 = 2 * l;
  #pragma unroll
  for (int j = 0; j < 4; ++j) {
    int r = wv * 4 + j;
    unsigned e = rowg[r];
    if ((int)e >= 0) {
      int g = e & 0xFFFF;
      int mi = (e >> 16) & 1;
      unsigned uw = *(const unsigned*)&Bs[((r * 4 + 0) << 7) + c2];
      unsigned iw = *(const unsigned*)&Bs[((r * 4 + 1) << 7) + c2];
      unsigned ow = *(const unsigned*)&Bs[((r * 4 + 2) << 7) + c2];
      unsigned gw = *(const unsigned*)&Bs[((r * 4 + 3) << 7) + c2];
      float2 ccv = *(const float2*)(child_c + (size_t)g * H + c2);
      float f0 = sigm(bf2f((unsigned short)(uw & 0xFFFF)));
      float f1 = sigm(bf2f((unsigned short)(uw >> 16)));
      float cr0 = f0 * ccv.x, cr1 = f1 * ccv.y;
      float h0, h1, cv0, cv1;
      if (mi) {
        float2 hp = *(const float2*)(h_prev + (size_t)g * H + c2);
        h0 = hp.x; h1 = hp.y; cv0 = cr0; cv1 = cr1;
      } else {
        float i0 = sigm(bf2f((unsigned short)(iw & 0xFFFF)));
        float i1 = sigm(bf2f((unsigned short)(iw >> 16)));
        float g0 = tanh_f(bf2f((unsigned short)(gw & 0xFFFF)));
        float g1 = tanh_f(bf2f((unsigned short)(gw >> 16)));
        float o0 = sigm(bf2f((unsigned short)(ow & 0xFFFF)));
        float o1 = sigm(bf2f((unsigned short)(ow >> 16)));
        cv0 = i0 * g0 + cr0;
        cv1 = i1 * g1 + cr1;
        h0 = o0 * tanh_f(cv0);
        h1 = o1 * tanh_f(cv1);
      }
      size_t gi = (size_t)g * H + c2;
      __builtin_nontemporal_store(h0, &out[gi]);
      __builtin_nontemporal_store(h1, &out[gi + 1]);
      __builtin_nontemporal_store(cv0, &out[NH + gi]);
      __builtin_nontemporal_store(cv1, &out[NH + gi + 1]);
    }
  }
}

extern "C" void kernel_launch(void* const* d_in, const int* in_sizes, int n_in,
                              void* d_out, int out_size, void* d_ws, size_t ws_size,
                              hipStream_t stream) {
  const float* child_h = (const float*)d_in[0];
  const float* child_c = (const float*)d_in[1];
  const float* e1      = (const float*)d_in[2];
  const float* e2      = (const float*)d_in[3];
  const float* h_prev  = (const float*)d_in[4];
  const int*   posp    = (const int*)d_in[5];
  const int*   depthp  = (const int*)d_in[6];
  const int*   maskp   = (const int*)d_in[7];
  const float* W_f     = (const float*)d_in[8];
  const float* b_f     = (const float*)d_in[9];
  const float* W_iou   = (const float*)d_in[10];
  const float* b_iou   = (const float*)d_in[11];
  float* out = (float*)d_out;
  int N = in_sizes[0] / H;
  int nhb = (N + 255) / 256;
  int maxb = NPOS + N / ROWSB;

  // ws layout
  unsigned short* wt = (unsigned short*)d_ws;          // 655360 * 2B
  int* hist2  = (int*)((char*)d_ws + (size_t)NPOS * 512 * H * 2);
  int* off2   = hist2 + nhb * 16;
  int* blkpos = off2 + nhb * 16;
  int* blkgs  = blkpos + maxb;
  int* blkcnt = blkgs + maxb;
  unsigned* order = (unsigned*)(blkcnt + maxb);

  int prep_blocks = NPOS * 16 + (NPOS * 384 * H) / 256 + nhb;
  hipLaunchKernelGGL(prep_wt, dim3(prep_blocks), dim3(256), 0, stream,
                     W_f, W_iou, wt, posp, hist2, N, nhb);
  hipLaunchKernelGGL(scan_build, dim3(1), dim3(640), 0, stream,
                     hist2, nhb, off2, blkpos, blkgs, blkcnt, maxb);
  hipLaunchKernelGGL(scatter_idx, dim3(nhb), dim3(256), 0, stream,
                     posp, depthp, maskp, off2, order, N);
  hipLaunchKernelGGL(tree_lstm_main, dim3(maxb), dim3(BLOCK), 0, stream,
                     child_h, child_c, e1, e2, h_prev,
                     b_f, b_iou, wt, order, blkpos, blkgs, blkcnt, out, N);
}

// Round 15
// 43.629 us; speedup vs baseline: 1.1919x; 1.0290x over previous
//
#include <hip/hip_runtime.h>

#define H 128
#define NPOS 10
#define ROWSB 32
#define BLOCK 512
#define NXCD 8

using bf16x8 = __attribute__((ext_vector_type(8))) short;
using f32x4  = __attribute__((ext_vector_type(4))) float;

__device__ __forceinline__ unsigned short f2bf(float f) {
  unsigned u = __float_as_uint(f);
  u += 0x7FFFu + ((u >> 16) & 1u);   // round-to-nearest-even
  return (unsigned short)(u >> 16);
}
__device__ __forceinline__ float bf2f(unsigned short s) {
  return __uint_as_float(((unsigned)s) << 16);
}
__device__ __forceinline__ float sigm(float x) {
  return __builtin_amdgcn_rcpf(1.0f + __builtin_amdgcn_exp2f(-1.44269504f * x));
}
__device__ __forceinline__ float tanh_f(float x) {
  return 2.0f * __builtin_amdgcn_rcpf(1.0f + __builtin_amdgcn_exp2f(-2.88539008f * x)) - 1.0f;
}

// K1: weights prep (k-major fragment layout) + per-block pos histogram.
// wt elem offset = (((p*4+kk)*4 + lhi)*512 + j)*8 + e  where k = kk*32+lhi*8+e,
// j<128 -> u-gate col j (W_f);  j>=128 -> iou row j-128 (W_iou).
__global__ void prep_wt(const float* __restrict__ Wf, const float* __restrict__ Wiou,
                        unsigned short* __restrict__ wt,
                        const int* __restrict__ posp, int* __restrict__ hist2,
                        int N, int nhb) {
  int b = blockIdx.x, t = threadIdx.x;
  if (b < NPOS * 16) {
    __shared__ float tile[32][33];
    int p = b >> 4, jt = (b >> 2) & 3, kt = b & 3;
    int tx = t & 31, ty = t >> 5;            // 32 x 8
    #pragma unroll
    for (int it = 0; it < 4; ++it) {
      int krow = kt * 32 + ty + it * 8;
      int j = jt * 32 + tx;
      tile[ty + it * 8][tx] = Wf[(size_t)(p * H + krow) * H + j];
    }
    __syncthreads();
    #pragma unroll
    for (int it = 0; it < 4; ++it) {
      int j2 = jt * 32 + ty + it * 8;        // u-gate col
      size_t dst = (((size_t)(p * 4 + kt) * 4 + (tx >> 3)) * 512 + j2) * 8 + (tx & 7);
      wt[dst] = f2bf(tile[tx][ty + it * 8]);
    }
  } else if (b < NPOS * 16 + (NPOS * 384 * H) / 256) {
    int id = (b - NPOS * 16) * 256 + t;      // < 10*384*128
    int p = id / 49152;
    int r = id - p * 49152;                  // (j-128)*128 + k
    int j = 128 + (r >> 7);
    int k = r & 127;
    float v = Wiou[(size_t)(r >> 7) * (NPOS * H) + p * H + k];
    size_t dst = (((size_t)(p * 4 + (k >> 5)) * 4 + ((k >> 3) & 3)) * 512 + j) * 8 + (k & 7);
    wt[dst] = f2bf(v);
  } else {
    int hb = b - (NPOS * 16 + (NPOS * 384 * H) / 256);
    __shared__ int c[NPOS];
    if (t < NPOS) c[t] = 0;
    __syncthreads();
    int i = hb * 256 + t;
    if (i < N) atomicAdd(&c[posp[i]], 1);    // LDS atomic only
    __syncthreads();
    if (t < NPOS) hist2[hb * 16 + t] = c[t];
  }
}

// K2: wave-parallel scans (10 waves, wave w owns pos w).
__global__ void scan_build(const int* __restrict__ hist2, int nhb,
                           int* __restrict__ off2,
                           int* __restrict__ blkpos, int* __restrict__ blkgs,
                           int* __restrict__ blkcnt, int maxb) {
  __shared__ int tot[NPOS], base[NPOS + 1], bb[NPOS + 1];
  int t = threadIdx.x;
  int w = t >> 6, l = t & 63;
  if (w < NPOS) {
    int b0 = 2 * l, b1 = 2 * l + 1;
    int a  = (b0 < nhb) ? hist2[b0 * 16 + w] : 0;
    int bv = (b1 < nhb) ? hist2[b1 * 16 + w] : 0;
    int s = a + bv, sc = s;
    #pragma unroll
    for (int off = 1; off < 64; off <<= 1) {
      int u = __shfl_up(sc, off);
      if (l >= off) sc += u;
    }
    int excl = sc - s;
    if (b0 < nhb) off2[b0 * 16 + w] = excl;
    if (b1 < nhb) off2[b1 * 16 + w] = excl + a;
    if (l == 63) tot[w] = sc;
  }
  __syncthreads();
  if (t == 0) {
    int run = 0, rb = 0;
    for (int p = 0; p < NPOS; ++p) {
      base[p] = run; bb[p] = rb;
      run += tot[p];
      rb += (tot[p] + ROWSB - 1) / ROWSB;
    }
    base[NPOS] = run; bb[NPOS] = rb;
  }
  __syncthreads();
  for (int i = t; i < nhb * NPOS; i += 640) {
    int b = i / NPOS, p = i - b * NPOS;
    off2[b * 16 + p] += base[p];
  }
  int nb = bb[NPOS];
  for (int b = t; b < maxb; b += 640) {
    if (b < nb) {
      int p = 0;
      while (bb[p + 1] <= b) ++p;
      int s = (b - bb[p]) * ROWSB;
      blkpos[b] = p;
      blkgs[b] = base[p] + s;
      blkcnt[b] = min(ROWSB, tot[p] - s);
    } else {
      blkpos[b] = -1;
    }
  }
}

// K3: scatter (LDS atomics + precomputed per-(block,pos) bases).
// order entry packs: g | mask<<16 | (depth==1)<<17 | (depth==2)<<18
__global__ void scatter_idx(const int* __restrict__ posp, const int* __restrict__ depthp,
                            const int* __restrict__ maskp, const int* __restrict__ off2,
                            unsigned* __restrict__ order, int N) {
  __shared__ int c[NPOS], basearr[NPOS];
  int hb = blockIdx.x, t = threadIdx.x;
  if (t < NPOS) { c[t] = 0; basearr[t] = off2[hb * 16 + t]; }
  __syncthreads();
  int i = hb * 256 + t;
  int p = -1, r = 0;
  unsigned e = 0;
  if (i < N) {
    p = posp[i];
    r = atomicAdd(&c[p], 1);                 // LDS atomic only
    int d = depthp[i];
    int mk = maskp[i];
    e = (unsigned)i | ((unsigned)mk << 16) |
        ((unsigned)(d == 1) << 17) | ((unsigned)(d == 2) << 18);
  }
  __syncthreads();
  if (p >= 0) order[basearr[p] + r] = e;
}

// K4: main (R14 structure) + bijective XCD block swizzle (T1/m204) +
// conflict-free gate-transpose swizzle.
__global__ __launch_bounds__(BLOCK, 3) void tree_lstm_main(
    const float* __restrict__ child_h, const float* __restrict__ child_c,
    const float* __restrict__ e1, const float* __restrict__ e2,
    const float* __restrict__ h_prev,
    const float* __restrict__ b_f, const float* __restrict__ b_iou,
    const unsigned short* __restrict__ wt,
    const unsigned* __restrict__ order, const int* __restrict__ blkpos,
    const int* __restrict__ blkgs, const int* __restrict__ blkcnt,
    float* __restrict__ out, int N, int nwg) {

  // bijective XCD swizzle: each XCD gets a contiguous chunk of sorted blocks
  int orig = blockIdx.x;
  int q = nwg / NXCD, rres = nwg % NXCD;
  int xcd = orig % NXCD, slot = orig / NXCD;
  int b = (xcd < rres ? xcd * (q + 1) : rres * (q + 1) + (xcd - rres) * q) + slot;

  const int p = blkpos[b];
  if (p < 0) return;
  const int gs = blkgs[b], cnth = blkcnt[b];

  __shared__ unsigned short hs[ROWSB * H];   // 8 KB, XOR-swizzled bf16 h_cat
  __shared__ unsigned short Bs[4 * 512 * 8]; // 32 KB: B slab; then gate-transpose
  __shared__ unsigned rowg[ROWSB];

  const int t = threadIdx.x;
  const int wv = t >> 6, l = t & 63;
  const int l15 = l & 15, lhi = l >> 4;
  const int colr = wv * 16 + l15;            // wave's output column 0..127

  if (t < ROWSB) rowg[t] = (t < cnth) ? order[gs + t] : 0xFFFFFFFFu;
  __syncthreads();

  // ---- stage A: 32 rows x 128 bf16 (512B contiguous per row) ----
  {
    int row = t >> 4, c8 = t & 15;
    unsigned e = rowg[row];
    float4 a0 = {0.f, 0.f, 0.f, 0.f}, a1 = {0.f, 0.f, 0.f, 0.f};
    if ((int)e >= 0) {
      int g = e & 0xFFFF;
      const float4* ph = (const float4*)(child_h + (size_t)g * H + c8 * 8);
      a0 = ph[0]; a1 = ph[1];
      if (e & (3u << 17)) {
        const float* ep = (e & (1u << 17)) ? e1 : e2;
        const float4* pe = (const float4*)(ep + (size_t)g * H + c8 * 8);
        float4 b0 = pe[0], b1 = pe[1];
        a0.x += b0.x; a0.y += b0.y; a0.z += b0.z; a0.w += b0.w;
        a1.x += b1.x; a1.y += b1.y; a1.z += b1.z; a1.w += b1.w;
      }
    }
    bf16x8 v;
    v[0] = (short)f2bf(a0.x); v[1] = (short)f2bf(a0.y);
    v[2] = (short)f2bf(a0.z); v[3] = (short)f2bf(a0.w);
    v[4] = (short)f2bf(a1.x); v[5] = (short)f2bf(a1.y);
    v[6] = (short)f2bf(a1.z); v[7] = (short)f2bf(a1.w);
    int wb = (row * 256 + c8 * 16) ^ ((row & 7) << 4);
    *(bf16x8*)((char*)hs + wb) = v;
  }
  __syncthreads();

  f32x4 acc[2][4] = {};
  const unsigned short* wtp = wt + (size_t)p * 65536;

  #pragma unroll
  for (int kk = 0; kk < 4; ++kk) {
    if (kk) __syncthreads();
    #pragma unroll
    for (int i = 0; i < 4; ++i) {
      int eo = (i * BLOCK + t) * 8;
      *(bf16x8*)(Bs + eo) = *(const bf16x8*)(wtp + kk * 16384 + eo);
    }
    __syncthreads();

    bf16x8 bfr[4];
    #pragma unroll
    for (int g4 = 0; g4 < 4; ++g4)
      bfr[g4] = *(const bf16x8*)(Bs + ((lhi * 512) + (g4 * 128 + colr)) * 8);

    #pragma unroll
    for (int c = 0; c < 2; ++c) {
      const int arow = c * 16 + l15;
      int rb = (arow * 256 + kk * 64 + lhi * 16) ^ ((arow & 7) << 4);
      bf16x8 afr = *(const bf16x8*)((const char*)hs + rb);
      #pragma unroll
      for (int g4 = 0; g4 < 4; ++g4)
        acc[c][g4] = __builtin_amdgcn_mfma_f32_16x16x32_bf16(afr, bfr[g4], acc[c][g4], 0, 0, 0);
    }
  }
  __syncthreads();                            // Bs reads done; safe to overwrite

  // ---- gate transpose into Bs, conflict-free column swizzle ----
  // addr(row_g, col) = row_g*128 + (col ^ (((row_g>>2)&3)<<3)); the 4 writers
  // of a (c,q,g4) group differ by 16 in row_g -> 4 distinct masks -> 4 banks.
  {
    const float bfv = b_f[p * H + colr];
    const float b_i = b_iou[colr], b_o = b_iou[H + colr], b_g = b_iou[2 * H + colr];
    #pragma unroll
    for (int c = 0; c < 2; ++c)
      #pragma unroll
      for (int q = 0; q < 4; ++q) {
        int r = c * 16 + lhi * 4 + q;
        #pragma unroll
        for (int g4 = 0; g4 < 4; ++g4) {
          int rg = r * 4 + g4;
          int col = colr ^ (((rg >> 2) & 3) << 3);
          float v = (g4 == 0) ? acc[c][0][q] + bfv :
                    (g4 == 1) ? acc[c][1][q] + b_i :
                    (g4 == 2) ? acc[c][2][q] + b_o : acc[c][3][q] + b_g;
          Bs[(rg << 7) + col] = f2bf(v);
        }
      }
  }
  __syncthreads();

  // ---- row-per-wave epilogue: 512B-contiguous gathers and stores ----
  const size_t NH = (size_t)N * H;
  const int c2 = 2 * l;
  #pragma unroll
  for (int j = 0; j < 4; ++j) {
    int r = wv * 4 + j;
    unsigned e = rowg[r];
    if ((int)e >= 0) {
      int g = e & 0xFFFF;
      int mi = (e >> 16) & 1;
      int rg0 = r * 4;
      unsigned uw = *(const unsigned*)&Bs[((rg0 + 0) << 7) + (c2 ^ ((((rg0 + 0) >> 2) & 3) << 3))];
      unsigned iw = *(const unsigned*)&Bs[((rg0 + 1) << 7) + (c2 ^ ((((rg0 + 1) >> 2) & 3) << 3))];
      unsigned ow = *(const unsigned*)&Bs[((rg0 + 2) << 7) + (c2 ^ ((((rg0 + 2) >> 2) & 3) << 3))];
      unsigned gw = *(const unsigned*)&Bs[((rg0 + 3) << 7) + (c2 ^ ((((rg0 + 3) >> 2) & 3) << 3))];
      float2 ccv = *(const float2*)(child_c + (size_t)g * H + c2);
      float f0 = sigm(bf2f((unsigned short)(uw & 0xFFFF)));
      float f1 = sigm(bf2f((unsigned short)(uw >> 16)));
      float cr0 = f0 * ccv.x, cr1 = f1 * ccv.y;
      float h0, h1, cv0, cv1;
      if (mi) {
        float2 hp = *(const float2*)(h_prev + (size_t)g * H + c2);
        h0 = hp.x; h1 = hp.y; cv0 = cr0; cv1 = cr1;
      } else {
        float i0 = sigm(bf2f((unsigned short)(iw & 0xFFFF)));
        float i1 = sigm(bf2f((unsigned short)(iw >> 16)));
        float g0 = tanh_f(bf2f((unsigned short)(gw & 0xFFFF)));
        float g1 = tanh_f(bf2f((unsigned short)(gw >> 16)));
        float o0 = sigm(bf2f((unsigned short)(ow & 0xFFFF)));
        float o1 = sigm(bf2f((unsigned short)(ow >> 16)));
        cv0 = i0 * g0 + cr0;
        cv1 = i1 * g1 + cr1;
        h0 = o0 * tanh_f(cv0);
        h1 = o1 * tanh_f(cv1);
      }
      size_t gi = (size_t)g * H + c2;
      __builtin_nontemporal_store(h0, &out[gi]);
      __builtin_nontemporal_store(h1, &out[gi + 1]);
      __builtin_nontemporal_store(cv0, &out[NH + gi]);
      __builtin_nontemporal_store(cv1, &out[NH + gi + 1]);
    }
  }
}

extern "C" void kernel_launch(void* const* d_in, const int* in_sizes, int n_in,
                              void* d_out, int out_size, void* d_ws, size_t ws_size,
                              hipStream_t stream) {
  const float* child_h = (const float*)d_in[0];
  const float* child_c = (const float*)d_in[1];
  const float* e1      = (const float*)d_in[2];
  const float* e2      = (const float*)d_in[3];
  const float* h_prev  = (const float*)d_in[4];
  const int*   posp    = (const int*)d_in[5];
  const int*   depthp  = (const int*)d_in[6];
  const int*   maskp   = (const int*)d_in[7];
  const float* W_f     = (const float*)d_in[8];
  const float* b_f     = (const float*)d_in[9];
  const float* W_iou   = (const float*)d_in[10];
  const float* b_iou   = (const float*)d_in[11];
  float* out = (float*)d_out;
  int N = in_sizes[0] / H;
  int nhb = (N + 255) / 256;
  int maxb = NPOS + N / ROWSB;

  // ws layout
  unsigned short* wt = (unsigned short*)d_ws;          // 655360 * 2B
  int* hist2  = (int*)((char*)d_ws + (size_t)NPOS * 512 * H * 2);
  int* off2   = hist2 + nhb * 16;
  int* blkpos = off2 + nhb * 16;
  int* blkgs  = blkpos + maxb;
  int* blkcnt = blkgs + maxb;
  unsigned* order = (unsigned*)(blkcnt + maxb);

  int prep_blocks = NPOS * 16 + (NPOS * 384 * H) / 256 + nhb;
  hipLaunchKernelGGL(prep_wt, dim3(prep_blocks), dim3(256), 0, stream,
                     W_f, W_iou, wt, posp, hist2, N, nhb);
  hipLaunchKernelGGL(scan_build, dim3(1), dim3(640), 0, stream,
                     hist2, nhb, off2, blkpos, blkgs, blkcnt, maxb);
  hipLaunchKernelGGL(scatter_idx, dim3(nhb), dim3(256), 0, stream,
                     posp, depthp, maskp, off2, order, N);
  hipLaunchKernelGGL(tree_lstm_main, dim3(maxb), dim3(BLOCK), 0, stream,
                     child_h, child_c, e1, e2, h_prev,
                     b_f, b_iou, wt, order, blkpos, blkgs, blkcnt, out, N, maxb);
}